// Round 7
// baseline (336.523 us; speedup 1.0000x reference)
//
#include <hip/hip_runtime.h>
#include <hip/hip_bf16.h>
#include <hip/hip_fp16.h>

// ---------- common types ----------
typedef __attribute__((ext_vector_type(8))) short bf16x8;      // 8 bf16 = 4 VGPR (MFMA A/B frag)
typedef __attribute__((ext_vector_type(8))) _Float16 f16x8;    // 8 f16  = 4 VGPR (MFMA A/B frag)
typedef __attribute__((ext_vector_type(4))) float f32x4;       // MFMA C/D frag

__device__ __forceinline__ short f2bf(float x) {
    unsigned u = __builtin_bit_cast(unsigned, x);
    u += 0x7fffu + ((u >> 16) & 1u);          // RNE
    return (short)(u >> 16);
}

// async global->LDS, 16B per lane. lds dst must be wave-uniform base; HW scatters lane*16.
__device__ __forceinline__ void load_lds16(const void* g, void* l) {
    __builtin_amdgcn_global_load_lds((const __attribute__((address_space(1))) unsigned int*)g,
                                     (__attribute__((address_space(3))) unsigned int*)l, 16, 0, 0);
}

// ---------- K0: fused converts ----------
__global__ void convert_qkv(const float* __restrict__ q, const float* __restrict__ k,
                            const float* __restrict__ v, short* __restrict__ qo,
                            short* __restrict__ ko, short* __restrict__ vo) {
    int i = blockIdx.x * 256 + threadIdx.x;   // 1048576 float4 per tensor, grid (4096,3)
    const float* s = blockIdx.y == 0 ? q : blockIdx.y == 1 ? k : v;
    short* d = blockIdx.y == 0 ? qo : blockIdx.y == 1 ? ko : vo;
    float4 val = reinterpret_cast<const float4*>(s)[i];
    short4 o; o.x = f2bf(val.x); o.y = f2bf(val.y); o.z = f2bf(val.z); o.w = f2bf(val.w);
    reinterpret_cast<short4*>(d)[i] = o;
}

__global__ void convert_w4(const float* __restrict__ w0, const float* __restrict__ w1,
                           const float* __restrict__ w2, const float* __restrict__ w3,
                           short* __restrict__ o0, short* __restrict__ o1,
                           short* __restrict__ o2, short* __restrict__ o3) {
    int i = blockIdx.x * 256 + threadIdx.x;   // 262144 float4 per tensor, grid (1024,4)
    const float* s = blockIdx.y == 0 ? w0 : blockIdx.y == 1 ? w1 : blockIdx.y == 2 ? w2 : w3;
    short* d = blockIdx.y == 0 ? o0 : blockIdx.y == 1 ? o1 : blockIdx.y == 2 ? o2 : o3;
    float4 val = reinterpret_cast<const float4*>(s)[i];
    short4 o; o.x = f2bf(val.x); o.y = f2bf(val.y); o.z = f2bf(val.z); o.w = f2bf(val.w);
    reinterpret_cast<short4*>(d)[i] = o;
}

__global__ void convert_f32_f16(const float* __restrict__ src, _Float16* __restrict__ dst, int n) {
    int i = blockIdx.x * blockDim.x + threadIdx.x;
    if (i < n) dst[i] = (_Float16)src[i];
}

// init d_out with broadcast bias (Wo split-K atomicAdds on top)
__global__ void init_out(const float* __restrict__ bo, float* __restrict__ out) {
    int i = blockIdx.x * 256 + threadIdx.x;   // 1048576 float4, grid 4096
    reinterpret_cast<float4*>(out)[i] = reinterpret_cast<const float4*>(bo)[i & 255];
}

// ---------- K1: geometry bias via MFMA projection; stores g (f16, [b][h][n][m]) ----------
__global__ void geom_kernel2(const float* __restrict__ boxes, const _Float16* __restrict__ Wgh,
                             const float* __restrict__ bg, __half* __restrict__ G) {
    const int tid = threadIdx.x;
    const int wave = tid >> 6, lane = tid & 63, quad = lane >> 4, l16 = lane & 15;
    const int m0 = blockIdx.x * 64;
    const int n = blockIdx.y;
    const int b = blockIdx.z;

    __shared__ __align__(16) _Float16 feat[4][16][72];
    __shared__ __align__(16) _Float16 gbuf[16][68];

    const int p = lane >> 2, c = lane & 3;
    const int m = m0 + wave * 16 + p;

    float4 bn = reinterpret_cast<const float4*>(boxes)[b * 512 + n];
    float4 bm = reinterpret_cast<const float4*>(boxes)[b * 512 + m];
    float cxn = (bn.x + bn.z) * 0.5f, cyn = (bn.y + bn.w) * 0.5f;
    float wn = bn.z - bn.x + 1.0f, hn = bn.w - bn.y + 1.0f;
    float cxm = (bm.x + bm.z) * 0.5f, cym = (bm.y + bm.w) * 0.5f;
    float wm = bm.z - bm.x + 1.0f, hm = bm.w - bm.y + 1.0f;

    float r;
    if (c == 0)      r = fmaxf(fabsf((cxn - cxm) / wn), 1e-3f);
    else if (c == 1) r = fmaxf(fabsf((cyn - cym) / hn), 1e-3f);
    else if (c == 2) r = wn / wm;
    else             r = hn / hm;
    float pos = __logf(r) * 100.0f;

    const float dm[8] = {1.0f, 0.42169651f, 0.17782794f, 0.07498942f,
                         0.03162278f, 0.01333521f, 0.00562341f, 0.00237137f};
    f16x8 sv8, cv8;
    #pragma unroll
    for (int f = 0; f < 8; ++f) {
        float th = pos * dm[f];
        sv8[f] = (_Float16)__sinf(th);
        cv8[f] = (_Float16)__cosf(th);
    }
    *(f16x8*)&feat[wave][p][c * 8]      = sv8;
    *(f16x8*)&feat[wave][p][32 + c * 8] = cv8;

    __syncthreads();

    f16x8 a0 = *(const f16x8*)&feat[wave][l16][quad * 8];
    f16x8 a1 = *(const f16x8*)&feat[wave][l16][32 + quad * 8];
    f16x8 b0 = *(const f16x8*)(Wgh + l16 * 64 + quad * 8);
    f16x8 b1 = *(const f16x8*)(Wgh + l16 * 64 + 32 + quad * 8);
    f32x4 acc = (f32x4){0.f, 0.f, 0.f, 0.f};
    acc = __builtin_amdgcn_mfma_f32_16x16x32_f16(a0, b0, acc, 0, 0, 0);
    acc = __builtin_amdgcn_mfma_f32_16x16x32_f16(a1, b1, acc, 0, 0, 0);

    float bgv = bg[l16];
    #pragma unroll
    for (int rr = 0; rr < 4; ++rr) {
        float g = fmaxf(acc[rr] + bgv, 1e-6f);        // relu + clip; store g itself
        gbuf[l16][wave * 16 + quad * 4 + rr] = (_Float16)g;
    }
    __syncthreads();

    const int h = tid >> 4, seg = tid & 15;
    ushort4 v = *(const ushort4*)&gbuf[h][seg * 4];
    *(ushort4*)&G[((long)((b * 16 + h) * 512 + n)) * 512 + m0 + seg * 4] = v;
}

// ---------- K2: ALL projections in one dispatch (Q, K, V), flat 768-block grid ----------
// blocks [0,512): Q/K proj  z=bid>>8: C[tok][out] = X . W^T  (bf16 out, col bias)
// blocks [512,768): V proj          : C[out][tok] = Wv . X^T (f16 Vt out, row bias, batch-split cols)
// All parts: K=1024, A/B row stride 1024. 128x128 tile, BK=32, global_load_lds w=16.
__global__ __launch_bounds__(256, 2)
void proj_all(const short* __restrict__ qkbf, const short* __restrict__ wqkb,
              const short* __restrict__ wvb, const short* __restrict__ vbf,
              const float* __restrict__ bq, const float* __restrict__ bk,
              const float* __restrict__ bv,
              short* __restrict__ QKh, _Float16* __restrict__ Vt) {
    __shared__ __align__(16) short As[4096];   // [128][32]
    __shared__ __align__(16) short Bs[4096];
    const int tid = threadIdx.x;
    const int wave = tid >> 6, lane = tid & 63, quad = lane >> 4, l16 = lane & 15;
    const int bid = blockIdx.x;

    const short *Ap, *Bp;
    int m0, n0, z = 0;
    bool isV = bid >= 512;
    if (!isV) {
        z = bid >> 8;
        int t = bid & 255;
        n0 = (t & 7) * 128; m0 = (t >> 3) * 128;
        Ap = qkbf + (long)z * 4194304 + (long)m0 * 1024;
        Bp = wqkb + (long)z * 1048576 + (long)n0 * 1024;
    } else {
        int t = bid - 512;
        n0 = (t & 31) * 128; m0 = (t >> 5) * 128;
        Ap = wvb + (long)m0 * 1024;
        Bp = vbf + (long)n0 * 1024;
    }

    f32x4 acc[4][4];
    #pragma unroll
    for (int mg = 0; mg < 4; ++mg)
        #pragma unroll
        for (int ng = 0; ng < 4; ++ng) acc[mg][ng] = (f32x4){0.f, 0.f, 0.f, 0.f};

    const int r0 = tid >> 2, kk = (tid & 3) * 8;
    const short* ga0 = Ap + (long)r0 * 1024 + kk;
    const short* ga1 = Ap + (long)(64 + r0) * 1024 + kk;
    const short* gb0 = Bp + (long)r0 * 1024 + kk;
    const short* gb1 = Bp + (long)(64 + r0) * 1024 + kk;
    short* la0 = As + wave * 512;
    short* la1 = As + 2048 + wave * 512;
    short* lb0 = Bs + wave * 512;
    short* lb1 = Bs + 2048 + wave * 512;

    const int mw = (wave >> 1) * 64, nw = (wave & 1) * 64;

    for (int k0 = 0; k0 < 1024; k0 += 32) {
        load_lds16(ga0 + k0, la0);
        load_lds16(ga1 + k0, la1);
        load_lds16(gb0 + k0, lb0);
        load_lds16(gb1 + k0, lb1);
        __syncthreads();
        bf16x8 a[4], bb[4];
        #pragma unroll
        for (int g = 0; g < 4; ++g) {
            a[g]  = *(const bf16x8*)&As[(mw + g * 16 + l16) * 32 + quad * 8];
            bb[g] = *(const bf16x8*)&Bs[(nw + g * 16 + l16) * 32 + quad * 8];
        }
        #pragma unroll
        for (int mg = 0; mg < 4; ++mg)
            #pragma unroll
            for (int ng = 0; ng < 4; ++ng)
                acc[mg][ng] = __builtin_amdgcn_mfma_f32_16x16x32_bf16(a[mg], bb[ng], acc[mg][ng], 0, 0, 0);
        __syncthreads();
    }

    #pragma unroll
    for (int mg = 0; mg < 4; ++mg)
        #pragma unroll
        for (int ng = 0; ng < 4; ++ng)
            #pragma unroll
            for (int r = 0; r < 4; ++r) {
                int row = m0 + mw + mg * 16 + quad * 4 + r;
                int col = n0 + nw + ng * 16 + l16;
                if (!isV) {
                    float v = acc[mg][ng][r] + (z ? bk[col] : bq[col]);
                    QKh[(long)z * 4194304 + (long)row * 1024 + col] = f2bf(v);
                } else {
                    float v = acc[mg][ng][r] + bv[row];
                    int bcol = col >> 9, lc = col & 511;    // token -> (batch, local)
                    Vt[(long)bcol * 524288 + (long)row * 512 + lc] = (_Float16)v;
                }
            }
}

// ---------- K3: flash attention, split-kv, 512 threads = 8 waves ----------
// waves 0-3: kv [0,256); waves 4-7: kv [256,512). Same 64 q-rows per block.
// Softmax is max-free (p = g*exp(s/8)): halves combine by pure addition via LDS.
__global__ __launch_bounds__(512, 8)
void flash_attn4(const short* __restrict__ Q, const short* __restrict__ Kh,
                 const _Float16* __restrict__ Vt, const __half* __restrict__ G,
                 short* __restrict__ O) {
    const int tid = threadIdx.x;
    const int wave = tid >> 6, lane = tid & 63, quad = lane >> 4, l16 = lane & 15;
    const int wq = wave & 3, half = wave >> 2;
    const int qt = blockIdx.x, h = blockIdx.y, b = blockIdx.z;

    __shared__ __align__(16) _Float16 Pbuf[8][16][72];   // per-wave private
    __shared__ __align__(16) float Obuf[4][16][64];      // half-1 partial O
    __shared__ float Rbuf[4][16];                        // half-1 partial row sums

    const int qrow = qt * 64 + wq * 16;
    const long qoff = ((long)(b * 512 + qrow + l16)) * 1024 + h * 64 + quad * 8;
    bf16x8 aq0 = *(const bf16x8*)(Q + qoff);
    bf16x8 aq1 = *(const bf16x8*)(Q + qoff + 32);

    const _Float16* Gq = (const _Float16*)G +
        ((long)((b * 16 + h) * 512 + qrow + l16)) * 512;

    f32x4 oacc[4];
    #pragma unroll
    for (int r = 0; r < 4; ++r) oacc[r] = (f32x4){0.f, 0.f, 0.f, 0.f};
    float rs = 0.f;   // row-sum for q = l16 (this half)

    for (int i = 0; i < 4; ++i) {
        const int kt = half * 4 + i;
        // g loads first (independent -> overlap the MFMA chain)
        f16x8 g0 = *(const f16x8*)(Gq + kt * 64 + quad * 8);
        f16x8 g1 = *(const f16x8*)(Gq + kt * 64 + 32 + quad * 8);
        // QK^T
        float s[4][4];
        #pragma unroll
        for (int nk = 0; nk < 4; ++nk) {
            const long koff = ((long)(b * 512 + kt * 64 + nk * 16 + l16)) * 1024 + h * 64 + quad * 8;
            bf16x8 bk0 = *(const bf16x8*)(Kh + koff);
            bf16x8 bk1 = *(const bf16x8*)(Kh + koff + 32);
            f32x4 sc = (f32x4){0.f, 0.f, 0.f, 0.f};
            sc = __builtin_amdgcn_mfma_f32_16x16x32_bf16(aq0, bk0, sc, 0, 0, 0);
            sc = __builtin_amdgcn_mfma_f32_16x16x32_bf16(aq1, bk1, sc, 0, 0, 0);
            #pragma unroll
            for (int r = 0; r < 4; ++r) s[nk][r] = sc[r];
        }
        // exp in C-layout -> wave-private Pbuf (no barrier)
        #pragma unroll
        for (int nk = 0; nk < 4; ++nk)
            #pragma unroll
            for (int r = 0; r < 4; ++r)
                Pbuf[wave][quad * 4 + r][nk * 16 + l16] = (_Float16)__expf(s[nk][r] * 0.125f);
        // A-frag read (q = l16, m contiguous), fold g
        f16x8 ep0 = *(const f16x8*)&Pbuf[wave][l16][quad * 8];
        f16x8 ep1 = *(const f16x8*)&Pbuf[wave][l16][32 + quad * 8];
        f16x8 gp0 = ep0 * g0;
        f16x8 gp1 = ep1 * g1;
        float part = 0.f;
        #pragma unroll
        for (int j = 0; j < 8; ++j) part += (float)gp0[j] + (float)gp1[j];
        rs += part;
        // PV (f16 MFMA)
        #pragma unroll
        for (int n4 = 0; n4 < 4; ++n4) {
            const long voff = ((long)(b * 1024 + h * 64 + n4 * 16 + l16)) * 512 + kt * 64 + quad * 8;
            f16x8 bv0 = *(const f16x8*)(Vt + voff);
            f16x8 bv1 = *(const f16x8*)(Vt + voff + 32);
            oacc[n4] = __builtin_amdgcn_mfma_f32_16x16x32_f16(gp0, bv0, oacc[n4], 0, 0, 0);
            oacc[n4] = __builtin_amdgcn_mfma_f32_16x16x32_f16(gp1, bv1, oacc[n4], 0, 0, 0);
        }
    }

    // reduce rs over the 4 quad-partners holding the same q = l16
    rs += __shfl_xor(rs, 16);
    rs += __shfl_xor(rs, 32);

    if (half == 1) {
        if (lane < 16) Rbuf[wq][l16] = rs;
        #pragma unroll
        for (int n4 = 0; n4 < 4; ++n4)
            #pragma unroll
            for (int r = 0; r < 4; ++r)
                Obuf[wq][quad * 4 + r][n4 * 16 + l16] = oacc[n4][r];
    }
    __syncthreads();
    if (half == 0) {
        rs += Rbuf[wq][l16];
        float li[4];
        #pragma unroll
        for (int r = 0; r < 4; ++r) li[r] = __shfl(rs, quad * 4 + r);
        #pragma unroll
        for (int n4 = 0; n4 < 4; ++n4)
            #pragma unroll
            for (int r = 0; r < 4; ++r) {
                float o = (oacc[n4][r] + Obuf[wq][quad * 4 + r][n4 * 16 + l16]) / li[r];
                O[((long)(b * 512 + qrow + quad * 4 + r)) * 1024 + h * 64 + n4 * 16 + l16] = f2bf(o);
            }
    }
}

// ---------- K4: Wo GEMM, split-K x2, atomicAdd into bias-initialized d_out ----------
__global__ __launch_bounds__(256, 2)
void gemm_wo(const short* __restrict__ Hd, const short* __restrict__ wob,
             float* __restrict__ out) {
    __shared__ __align__(16) short As[4096];
    __shared__ __align__(16) short Bs[4096];
    const int tid = threadIdx.x;
    const int wave = tid >> 6, lane = tid & 63, quad = lane >> 4, l16 = lane & 15;
    const int m0 = blockIdx.y * 128, n0 = blockIdx.x * 128;
    const int kz = blockIdx.z * 512;
    const short* Ap = Hd + (long)m0 * 1024 + kz;
    const short* Bp = wob + (long)n0 * 1024 + kz;

    f32x4 acc[4][4];
    #pragma unroll
    for (int mg = 0; mg < 4; ++mg)
        #pragma unroll
        for (int ng = 0; ng < 4; ++ng) acc[mg][ng] = (f32x4){0.f, 0.f, 0.f, 0.f};

    const int r0 = tid >> 2, kk = (tid & 3) * 8;
    const short* ga0 = Ap + (long)r0 * 1024 + kk;
    const short* ga1 = Ap + (long)(64 + r0) * 1024 + kk;
    const short* gb0 = Bp + (long)r0 * 1024 + kk;
    const short* gb1 = Bp + (long)(64 + r0) * 1024 + kk;
    short* la0 = As + wave * 512;
    short* la1 = As + 2048 + wave * 512;
    short* lb0 = Bs + wave * 512;
    short* lb1 = Bs + 2048 + wave * 512;

    const int mw = (wave >> 1) * 64, nw = (wave & 1) * 64;

    for (int k0 = 0; k0 < 512; k0 += 32) {
        load_lds16(ga0 + k0, la0);
        load_lds16(ga1 + k0, la1);
        load_lds16(gb0 + k0, lb0);
        load_lds16(gb1 + k0, lb1);
        __syncthreads();
        bf16x8 a[4], bb[4];
        #pragma unroll
        for (int g = 0; g < 4; ++g) {
            a[g]  = *(const bf16x8*)&As[(mw + g * 16 + l16) * 32 + quad * 8];
            bb[g] = *(const bf16x8*)&Bs[(nw + g * 16 + l16) * 32 + quad * 8];
        }
        #pragma unroll
        for (int mg = 0; mg < 4; ++mg)
            #pragma unroll
            for (int ng = 0; ng < 4; ++ng)
                acc[mg][ng] = __builtin_amdgcn_mfma_f32_16x16x32_bf16(a[mg], bb[ng], acc[mg][ng], 0, 0, 0);
        __syncthreads();
    }

    #pragma unroll
    for (int mg = 0; mg < 4; ++mg)
        #pragma unroll
        for (int ng = 0; ng < 4; ++ng)
            #pragma unroll
            for (int r = 0; r < 4; ++r) {
                int row = m0 + mw + mg * 16 + quad * 4 + r;
                int col = n0 + nw + ng * 16 + l16;
                atomicAdd(out + (long)row * 1024 + col, acc[mg][ng][r]);
            }
}

// ---------- launch ----------
extern "C" void kernel_launch(void* const* d_in, const int* in_sizes, int n_in,
                              void* d_out, int out_size, void* d_ws, size_t ws_size,
                              hipStream_t stream) {
    const float* queries = (const float*)d_in[0];
    const float* keys    = (const float*)d_in[1];
    const float* values  = (const float*)d_in[2];
    const float* boxes   = (const float*)d_in[3];
    const float* bq = (const float*)d_in[5];
    const float* bk = (const float*)d_in[7];
    const float* bv = (const float*)d_in[9];
    const float* bo = (const float*)d_in[11];
    const float* Wg = (const float*)d_in[12];
    const float* bg = (const float*)d_in[13];

    char* ws = (char*)d_ws;
    short* qbf = (short*)(ws + 0);           // [8192][1024]: queries rows 0..4095, keys 4096..8191
    short* kbf = (short*)(ws + 8388608);
    short* vbf = (short*)(ws + 16777216);
    short* wqb = (short*)(ws + 25165824);    // wqb/wkb adjacent (z-stride 1048576 elems)
    short* wkb = (short*)(ws + 27262976);
    short* wvb = (short*)(ws + 29360128);
    short* wob = (short*)(ws + 31457280);
    short* Qh  = (short*)(ws + 33554432);    // Qh/Kh adjacent (z-stride 4194304 elems)
    _Float16* Vt = (_Float16*)(ws + 50331648);  // [b][1024 out][512 tok] f16
    short* Hd  = (short*)(ws + 58720256);    // hidden [4096][1024]
    __half* G  = (__half*)(ws + 67108864);   // g [b][h][512][512] f16, 67 MB
    _Float16* Wgh = (_Float16*)(ws + 33554432);  // overlaps Qh (dead before proj)

    convert_qkv<<<dim3(4096, 3), 256, 0, stream>>>(queries, keys, values, qbf, kbf, vbf);
    convert_w4<<<dim3(1024, 4), 256, 0, stream>>>((const float*)d_in[4], (const float*)d_in[6],
                                                  (const float*)d_in[8], (const float*)d_in[10],
                                                  wqb, wkb, wvb, wob);
    convert_f32_f16<<<4, 256, 0, stream>>>(Wg, Wgh, 1024);
    init_out<<<4096, 256, 0, stream>>>(bo, (float*)d_out);

    geom_kernel2<<<dim3(8, 512, 8), 256, 0, stream>>>(boxes, Wgh, bg, G);

    // all projections: 768 blocks (Q:256, K:256, V:256)
    proj_all<<<768, 256, 0, stream>>>(qbf, wqb, wvb, vbf, bq, bk, bv, Qh, Vt);

    flash_attn4<<<dim3(8, 16, 8), 512, 0, stream>>>(Qh, Qh + 4194304, Vt, G, Hd);

    // output projection, split-K x2, atomic accumulate onto bias-initialized d_out
    gemm_wo<<<dim3(8, 32, 2), 256, 0, stream>>>(Hd, wob, (float*)d_out);
}

// Round 8
// 306.035 us; speedup vs baseline: 1.0996x; 1.0996x over previous
//
#include <hip/hip_runtime.h>
#include <hip/hip_bf16.h>
#include <hip/hip_fp16.h>

// ---------- common types ----------
typedef __attribute__((ext_vector_type(8))) short bf16x8;      // 8 bf16 = 4 VGPR (MFMA A/B frag)
typedef __attribute__((ext_vector_type(8))) _Float16 f16x8;    // 8 f16  = 4 VGPR (MFMA A/B frag)
typedef __attribute__((ext_vector_type(4))) float f32x4;       // MFMA C/D frag

__device__ __forceinline__ short f2bf(float x) {
    unsigned u = __builtin_bit_cast(unsigned, x);
    u += 0x7fffu + ((u >> 16) & 1u);          // RNE
    return (short)(u >> 16);
}

// async global->LDS, 16B per lane. lds dst must be wave-uniform base; HW scatters lane*16.
__device__ __forceinline__ void load_lds16(const void* g, void* l) {
    __builtin_amdgcn_global_load_lds((const __attribute__((address_space(1))) unsigned int*)g,
                                     (__attribute__((address_space(3))) unsigned int*)l, 16, 0, 0);
}

// ---------- K0: fused converts ----------
__global__ void convert_qkv(const float* __restrict__ q, const float* __restrict__ k,
                            const float* __restrict__ v, short* __restrict__ qo,
                            short* __restrict__ ko, short* __restrict__ vo) {
    int i = blockIdx.x * 256 + threadIdx.x;   // 1048576 float4 per tensor, grid (4096,3)
    const float* s = blockIdx.y == 0 ? q : blockIdx.y == 1 ? k : v;
    short* d = blockIdx.y == 0 ? qo : blockIdx.y == 1 ? ko : vo;
    float4 val = reinterpret_cast<const float4*>(s)[i];
    short4 o; o.x = f2bf(val.x); o.y = f2bf(val.y); o.z = f2bf(val.z); o.w = f2bf(val.w);
    reinterpret_cast<short4*>(d)[i] = o;
}

__global__ void convert_w4(const float* __restrict__ w0, const float* __restrict__ w1,
                           const float* __restrict__ w2, const float* __restrict__ w3,
                           short* __restrict__ o0, short* __restrict__ o1,
                           short* __restrict__ o2, short* __restrict__ o3) {
    int i = blockIdx.x * 256 + threadIdx.x;   // 262144 float4 per tensor, grid (1024,4)
    const float* s = blockIdx.y == 0 ? w0 : blockIdx.y == 1 ? w1 : blockIdx.y == 2 ? w2 : w3;
    short* d = blockIdx.y == 0 ? o0 : blockIdx.y == 1 ? o1 : blockIdx.y == 2 ? o2 : o3;
    float4 val = reinterpret_cast<const float4*>(s)[i];
    short4 o; o.x = f2bf(val.x); o.y = f2bf(val.y); o.z = f2bf(val.z); o.w = f2bf(val.w);
    reinterpret_cast<short4*>(d)[i] = o;
}

__global__ void convert_f32_f16(const float* __restrict__ src, _Float16* __restrict__ dst, int n) {
    int i = blockIdx.x * blockDim.x + threadIdx.x;
    if (i < n) dst[i] = (_Float16)src[i];
}

// ---------- K1: geometry bias via MFMA projection; stores g (f16, [b][h][n][m]) ----------
__global__ void geom_kernel2(const float* __restrict__ boxes, const _Float16* __restrict__ Wgh,
                             const float* __restrict__ bg, __half* __restrict__ G) {
    const int tid = threadIdx.x;
    const int wave = tid >> 6, lane = tid & 63, quad = lane >> 4, l16 = lane & 15;
    const int m0 = blockIdx.x * 64;
    const int n = blockIdx.y;
    const int b = blockIdx.z;

    __shared__ __align__(16) _Float16 feat[4][16][72];
    __shared__ __align__(16) _Float16 gbuf[16][68];

    const int p = lane >> 2, c = lane & 3;
    const int m = m0 + wave * 16 + p;

    float4 bn = reinterpret_cast<const float4*>(boxes)[b * 512 + n];
    float4 bm = reinterpret_cast<const float4*>(boxes)[b * 512 + m];
    float cxn = (bn.x + bn.z) * 0.5f, cyn = (bn.y + bn.w) * 0.5f;
    float wn = bn.z - bn.x + 1.0f, hn = bn.w - bn.y + 1.0f;
    float cxm = (bm.x + bm.z) * 0.5f, cym = (bm.y + bm.w) * 0.5f;
    float wm = bm.z - bm.x + 1.0f, hm = bm.w - bm.y + 1.0f;

    float r;
    if (c == 0)      r = fmaxf(fabsf((cxn - cxm) / wn), 1e-3f);
    else if (c == 1) r = fmaxf(fabsf((cyn - cym) / hn), 1e-3f);
    else if (c == 2) r = wn / wm;
    else             r = hn / hm;
    float pos = __logf(r) * 100.0f;

    const float dm[8] = {1.0f, 0.42169651f, 0.17782794f, 0.07498942f,
                         0.03162278f, 0.01333521f, 0.00562341f, 0.00237137f};
    f16x8 sv8, cv8;
    #pragma unroll
    for (int f = 0; f < 8; ++f) {
        float th = pos * dm[f];
        sv8[f] = (_Float16)__sinf(th);
        cv8[f] = (_Float16)__cosf(th);
    }
    *(f16x8*)&feat[wave][p][c * 8]      = sv8;
    *(f16x8*)&feat[wave][p][32 + c * 8] = cv8;

    __syncthreads();

    f16x8 a0 = *(const f16x8*)&feat[wave][l16][quad * 8];
    f16x8 a1 = *(const f16x8*)&feat[wave][l16][32 + quad * 8];
    f16x8 b0 = *(const f16x8*)(Wgh + l16 * 64 + quad * 8);
    f16x8 b1 = *(const f16x8*)(Wgh + l16 * 64 + 32 + quad * 8);
    f32x4 acc = (f32x4){0.f, 0.f, 0.f, 0.f};
    acc = __builtin_amdgcn_mfma_f32_16x16x32_f16(a0, b0, acc, 0, 0, 0);
    acc = __builtin_amdgcn_mfma_f32_16x16x32_f16(a1, b1, acc, 0, 0, 0);

    float bgv = bg[l16];
    #pragma unroll
    for (int rr = 0; rr < 4; ++rr) {
        float g = fmaxf(acc[rr] + bgv, 1e-6f);        // relu + clip; store g itself
        gbuf[l16][wave * 16 + quad * 4 + rr] = (_Float16)g;
    }
    __syncthreads();

    const int h = tid >> 4, seg = tid & 15;
    ushort4 v = *(const ushort4*)&gbuf[h][seg * 4];
    *(ushort4*)&G[((long)((b * 16 + h) * 512 + n)) * 512 + m0 + seg * 4] = v;
}

// ---------- K2: ALL projections in one dispatch (Q, K, V), flat 768-block grid ----------
__global__ __launch_bounds__(256, 2)
void proj_all(const short* __restrict__ qkbf, const short* __restrict__ wqkb,
              const short* __restrict__ wvb, const short* __restrict__ vbf,
              const float* __restrict__ bq, const float* __restrict__ bk,
              const float* __restrict__ bv,
              short* __restrict__ QKh, _Float16* __restrict__ Vt) {
    __shared__ __align__(16) short As[4096];   // [128][32]
    __shared__ __align__(16) short Bs[4096];
    const int tid = threadIdx.x;
    const int wave = tid >> 6, lane = tid & 63, quad = lane >> 4, l16 = lane & 15;
    const int bid = blockIdx.x;

    const short *Ap, *Bp;
    int m0, n0, z = 0;
    bool isV = bid >= 512;
    if (!isV) {
        z = bid >> 8;
        int t = bid & 255;
        n0 = (t & 7) * 128; m0 = (t >> 3) * 128;
        Ap = qkbf + (long)z * 4194304 + (long)m0 * 1024;
        Bp = wqkb + (long)z * 1048576 + (long)n0 * 1024;
    } else {
        int t = bid - 512;
        n0 = (t & 31) * 128; m0 = (t >> 5) * 128;
        Ap = wvb + (long)m0 * 1024;
        Bp = vbf + (long)n0 * 1024;
    }

    f32x4 acc[4][4];
    #pragma unroll
    for (int mg = 0; mg < 4; ++mg)
        #pragma unroll
        for (int ng = 0; ng < 4; ++ng) acc[mg][ng] = (f32x4){0.f, 0.f, 0.f, 0.f};

    const int r0 = tid >> 2, kk = (tid & 3) * 8;
    const short* ga0 = Ap + (long)r0 * 1024 + kk;
    const short* ga1 = Ap + (long)(64 + r0) * 1024 + kk;
    const short* gb0 = Bp + (long)r0 * 1024 + kk;
    const short* gb1 = Bp + (long)(64 + r0) * 1024 + kk;
    short* la0 = As + wave * 512;
    short* la1 = As + 2048 + wave * 512;
    short* lb0 = Bs + wave * 512;
    short* lb1 = Bs + 2048 + wave * 512;

    const int mw = (wave >> 1) * 64, nw = (wave & 1) * 64;

    for (int k0 = 0; k0 < 1024; k0 += 32) {
        load_lds16(ga0 + k0, la0);
        load_lds16(ga1 + k0, la1);
        load_lds16(gb0 + k0, lb0);
        load_lds16(gb1 + k0, lb1);
        __syncthreads();
        bf16x8 a[4], bb[4];
        #pragma unroll
        for (int g = 0; g < 4; ++g) {
            a[g]  = *(const bf16x8*)&As[(mw + g * 16 + l16) * 32 + quad * 8];
            bb[g] = *(const bf16x8*)&Bs[(nw + g * 16 + l16) * 32 + quad * 8];
        }
        #pragma unroll
        for (int mg = 0; mg < 4; ++mg)
            #pragma unroll
            for (int ng = 0; ng < 4; ++ng)
                acc[mg][ng] = __builtin_amdgcn_mfma_f32_16x16x32_bf16(a[mg], bb[ng], acc[mg][ng], 0, 0, 0);
        __syncthreads();
    }

    #pragma unroll
    for (int mg = 0; mg < 4; ++mg)
        #pragma unroll
        for (int ng = 0; ng < 4; ++ng)
            #pragma unroll
            for (int r = 0; r < 4; ++r) {
                int row = m0 + mw + mg * 16 + quad * 4 + r;
                int col = n0 + nw + ng * 16 + l16;
                if (!isV) {
                    float v = acc[mg][ng][r] + (z ? bk[col] : bq[col]);
                    QKh[(long)z * 4194304 + (long)row * 1024 + col] = f2bf(v);
                } else {
                    float v = acc[mg][ng][r] + bv[row];
                    int bcol = col >> 9, lc = col & 511;    // token -> (batch, local)
                    Vt[(long)bcol * 524288 + (long)row * 512 + lc] = (_Float16)v;
                }
            }
}

// ---------- K3: flash attention, split-kv, register-pipelined loads ----------
// 512 thr = 8 waves; waves 0-3: kv [0,256), waves 4-7: kv [256,512); same 64 q-rows.
// Fully unrolled 4-iter loop: K-tile for i+1 prefetched right after i's QK-MFMAs;
// g double-buffered one iteration ahead. launch_bounds(512,4): VGPR<=128, no spill.
__global__ __launch_bounds__(512, 4)
void flash_attn5(const short* __restrict__ Q, const short* __restrict__ Kh,
                 const _Float16* __restrict__ Vt, const __half* __restrict__ G,
                 short* __restrict__ O) {
    const int tid = threadIdx.x;
    const int wave = tid >> 6, lane = tid & 63, quad = lane >> 4, l16 = lane & 15;
    const int wq = wave & 3, half = wave >> 2;
    const int qt = blockIdx.x, h = blockIdx.y, b = blockIdx.z;

    __shared__ __align__(16) _Float16 Pbuf[8][16][72];   // per-wave private
    __shared__ __align__(16) float Obuf[4][16][64];      // half-1 partial O
    __shared__ float Rbuf[4][16];                        // half-1 partial row sums

    const int qrow = qt * 64 + wq * 16;
    const long qoff = ((long)(b * 512 + qrow + l16)) * 1024 + h * 64 + quad * 8;
    bf16x8 aq0 = *(const bf16x8*)(Q + qoff);
    bf16x8 aq1 = *(const bf16x8*)(Q + qoff + 32);

    // this half's slices
    const _Float16* Gq = (const _Float16*)G +
        ((long)((b * 16 + h) * 512 + qrow + l16)) * 512 + half * 256;
    const short* Kb = Kh + ((long)(b * 512 + half * 256)) * 1024 + h * 64 + quad * 8;

    // g double-buffer: iteration 0
    f16x8 gA = *(const f16x8*)(Gq + quad * 8);
    f16x8 gB = *(const f16x8*)(Gq + 32 + quad * 8);
    // K tile for iteration 0
    bf16x8 kf0[4], kf1[4];
    #pragma unroll
    for (int nk = 0; nk < 4; ++nk) {
        const long ko = (long)(nk * 16 + l16) * 1024;
        kf0[nk] = *(const bf16x8*)(Kb + ko);
        kf1[nk] = *(const bf16x8*)(Kb + ko + 32);
    }

    f32x4 oacc[4];
    #pragma unroll
    for (int r = 0; r < 4; ++r) oacc[r] = (f32x4){0.f, 0.f, 0.f, 0.f};
    float rs = 0.f;   // row-sum for q = l16 (this half)

    #pragma unroll
    for (int i = 0; i < 4; ++i) {
        const int kt = half * 4 + i;
        // QK^T consumes current K tile
        f32x4 sc[4];
        #pragma unroll
        for (int nk = 0; nk < 4; ++nk) {
            f32x4 s = (f32x4){0.f, 0.f, 0.f, 0.f};
            s = __builtin_amdgcn_mfma_f32_16x16x32_bf16(aq0, kf0[nk], s, 0, 0, 0);
            s = __builtin_amdgcn_mfma_f32_16x16x32_bf16(aq1, kf1[nk], s, 0, 0, 0);
            sc[nk] = s;
        }
        // prefetch next iteration's K tile + g (full-iteration latency cover)
        f16x8 gA1, gB1;
        if (i < 3) {
            #pragma unroll
            for (int nk = 0; nk < 4; ++nk) {
                const long ko = (long)((i + 1) * 64 + nk * 16 + l16) * 1024;
                kf0[nk] = *(const bf16x8*)(Kb + ko);
                kf1[nk] = *(const bf16x8*)(Kb + ko + 32);
            }
            gA1 = *(const f16x8*)(Gq + (i + 1) * 64 + quad * 8);
            gB1 = *(const f16x8*)(Gq + (i + 1) * 64 + 32 + quad * 8);
        }
        // exp in C-layout -> wave-private Pbuf (no barrier)
        #pragma unroll
        for (int nk = 0; nk < 4; ++nk)
            #pragma unroll
            for (int r = 0; r < 4; ++r)
                Pbuf[wave][quad * 4 + r][nk * 16 + l16] = (_Float16)__expf(sc[nk][r] * 0.125f);
        // A-frag read (q = l16, m contiguous), fold g
        f16x8 ep0 = *(const f16x8*)&Pbuf[wave][l16][quad * 8];
        f16x8 ep1 = *(const f16x8*)&Pbuf[wave][l16][32 + quad * 8];
        f16x8 gp0 = ep0 * gA;
        f16x8 gp1 = ep1 * gB;
        float part = 0.f;
        #pragma unroll
        for (int j = 0; j < 8; ++j) part += (float)gp0[j] + (float)gp1[j];
        rs += part;
        // PV (f16 MFMA), V loads direct (L2-resident after first touch)
        #pragma unroll
        for (int n4 = 0; n4 < 4; ++n4) {
            const long voff = ((long)(b * 1024 + h * 64 + n4 * 16 + l16)) * 512 + kt * 64 + quad * 8;
            f16x8 bv0 = *(const f16x8*)(Vt + voff);
            f16x8 bv1 = *(const f16x8*)(Vt + voff + 32);
            oacc[n4] = __builtin_amdgcn_mfma_f32_16x16x32_f16(gp0, bv0, oacc[n4], 0, 0, 0);
            oacc[n4] = __builtin_amdgcn_mfma_f32_16x16x32_f16(gp1, bv1, oacc[n4], 0, 0, 0);
        }
        gA = gA1; gB = gB1;
    }

    // reduce rs over the 4 quad-partners holding the same q = l16
    rs += __shfl_xor(rs, 16);
    rs += __shfl_xor(rs, 32);

    if (half == 1) {
        if (lane < 16) Rbuf[wq][l16] = rs;
        #pragma unroll
        for (int n4 = 0; n4 < 4; ++n4)
            #pragma unroll
            for (int r = 0; r < 4; ++r)
                Obuf[wq][quad * 4 + r][n4 * 16 + l16] = oacc[n4][r];
    }
    __syncthreads();
    if (half == 0) {
        rs += Rbuf[wq][l16];
        float li[4];
        #pragma unroll
        for (int r = 0; r < 4; ++r) li[r] = __shfl(rs, quad * 4 + r);
        #pragma unroll
        for (int n4 = 0; n4 < 4; ++n4)
            #pragma unroll
            for (int r = 0; r < 4; ++r) {
                float o = (oacc[n4][r] + Obuf[wq][quad * 4 + r][n4 * 16 + l16]) / li[r];
                O[((long)(b * 512 + qrow + quad * 4 + r)) * 1024 + h * 64 + n4 * 16 + l16] = f2bf(o);
            }
    }
}

// ---------- K4: Wo GEMM, full-K, f32 out + bias (no atomics) ----------
__global__ __launch_bounds__(256, 2)
void gemm_out(const short* __restrict__ Hd, const short* __restrict__ wob,
              const float* __restrict__ bo, float* __restrict__ out) {
    __shared__ __align__(16) short As[4096];
    __shared__ __align__(16) short Bs[4096];
    const int tid = threadIdx.x;
    const int wave = tid >> 6, lane = tid & 63, quad = lane >> 4, l16 = lane & 15;
    const int m0 = blockIdx.y * 128, n0 = blockIdx.x * 128;
    const short* Ap = Hd + (long)m0 * 1024;
    const short* Bp = wob + (long)n0 * 1024;

    f32x4 acc[4][4];
    #pragma unroll
    for (int mg = 0; mg < 4; ++mg)
        #pragma unroll
        for (int ng = 0; ng < 4; ++ng) acc[mg][ng] = (f32x4){0.f, 0.f, 0.f, 0.f};

    const int r0 = tid >> 2, kk = (tid & 3) * 8;
    const short* ga0 = Ap + (long)r0 * 1024 + kk;
    const short* ga1 = Ap + (long)(64 + r0) * 1024 + kk;
    const short* gb0 = Bp + (long)r0 * 1024 + kk;
    const short* gb1 = Bp + (long)(64 + r0) * 1024 + kk;
    short* la0 = As + wave * 512;
    short* la1 = As + 2048 + wave * 512;
    short* lb0 = Bs + wave * 512;
    short* lb1 = Bs + 2048 + wave * 512;

    const int mw = (wave >> 1) * 64, nw = (wave & 1) * 64;

    for (int k0 = 0; k0 < 1024; k0 += 32) {
        load_lds16(ga0 + k0, la0);
        load_lds16(ga1 + k0, la1);
        load_lds16(gb0 + k0, lb0);
        load_lds16(gb1 + k0, lb1);
        __syncthreads();
        bf16x8 a[4], bb[4];
        #pragma unroll
        for (int g = 0; g < 4; ++g) {
            a[g]  = *(const bf16x8*)&As[(mw + g * 16 + l16) * 32 + quad * 8];
            bb[g] = *(const bf16x8*)&Bs[(nw + g * 16 + l16) * 32 + quad * 8];
        }
        #pragma unroll
        for (int mg = 0; mg < 4; ++mg)
            #pragma unroll
            for (int ng = 0; ng < 4; ++ng)
                acc[mg][ng] = __builtin_amdgcn_mfma_f32_16x16x32_bf16(a[mg], bb[ng], acc[mg][ng], 0, 0, 0);
        __syncthreads();
    }

    #pragma unroll
    for (int mg = 0; mg < 4; ++mg)
        #pragma unroll
        for (int ng = 0; ng < 4; ++ng)
            #pragma unroll
            for (int r = 0; r < 4; ++r) {
                int row = m0 + mw + mg * 16 + quad * 4 + r;
                int col = n0 + nw + ng * 16 + l16;
                out[(long)row * 1024 + col] = acc[mg][ng][r] + bo[col];
            }
}

// ---------- launch ----------
extern "C" void kernel_launch(void* const* d_in, const int* in_sizes, int n_in,
                              void* d_out, int out_size, void* d_ws, size_t ws_size,
                              hipStream_t stream) {
    const float* queries = (const float*)d_in[0];
    const float* keys    = (const float*)d_in[1];
    const float* values  = (const float*)d_in[2];
    const float* boxes   = (const float*)d_in[3];
    const float* bq = (const float*)d_in[5];
    const float* bk = (const float*)d_in[7];
    const float* bv = (const float*)d_in[9];
    const float* bo = (const float*)d_in[11];
    const float* Wg = (const float*)d_in[12];
    const float* bg = (const float*)d_in[13];

    char* ws = (char*)d_ws;
    short* qbf = (short*)(ws + 0);
    short* kbf = (short*)(ws + 8388608);
    short* vbf = (short*)(ws + 16777216);
    short* wqb = (short*)(ws + 25165824);    // wqb/wkb adjacent (z-stride 1048576 elems)
    short* wkb = (short*)(ws + 27262976);
    short* wvb = (short*)(ws + 29360128);
    short* wob = (short*)(ws + 31457280);
    short* Qh  = (short*)(ws + 33554432);    // Qh/Kh adjacent (z-stride 4194304 elems)
    _Float16* Vt = (_Float16*)(ws + 50331648);  // [b][1024 out][512 tok] f16
    short* Hd  = (short*)(ws + 58720256);    // hidden [4096][1024]
    __half* G  = (__half*)(ws + 67108864);   // g [b][h][512][512] f16, 67 MB
    _Float16* Wgh = (_Float16*)(ws + 33554432);  // overlaps Qh (dead before proj)

    convert_qkv<<<dim3(4096, 3), 256, 0, stream>>>(queries, keys, values, qbf, kbf, vbf);
    convert_w4<<<dim3(1024, 4), 256, 0, stream>>>((const float*)d_in[4], (const float*)d_in[6],
                                                  (const float*)d_in[8], (const float*)d_in[10],
                                                  wqb, wkb, wvb, wob);
    convert_f32_f16<<<4, 256, 0, stream>>>(Wg, Wgh, 1024);

    geom_kernel2<<<dim3(8, 512, 8), 256, 0, stream>>>(boxes, Wgh, bg, G);

    // all projections: 768 blocks (Q:256, K:256, V:256)
    proj_all<<<768, 256, 0, stream>>>(qbf, wqb, wvb, vbf, bq, bk, bv, Qh, Vt);

    flash_attn5<<<dim3(8, 16, 8), 512, 0, stream>>>(Qh, Qh + 4194304, Vt, G, Hd);

    // output projection -> f32 + bias
    gemm_out<<<dim3(8, 32), 256, 0, stream>>>(Hd, wob, bo, (float*)d_out);
}

// Round 9
// 280.490 us; speedup vs baseline: 1.1998x; 1.0911x over previous
//
#include <hip/hip_runtime.h>
#include <hip/hip_bf16.h>
#include <hip/hip_fp16.h>

// ---------- common types ----------
typedef __attribute__((ext_vector_type(8))) short bf16x8;      // 8 bf16 = 4 VGPR (MFMA A/B frag)
typedef __attribute__((ext_vector_type(8))) _Float16 f16x8;    // 8 f16  = 4 VGPR (MFMA A/B frag)
typedef __attribute__((ext_vector_type(4))) float f32x4;       // MFMA C/D frag
typedef __attribute__((ext_vector_type(8))) short short8;      // 16B chunk

__device__ __forceinline__ short f2bf(float x) {
    unsigned u = __builtin_bit_cast(unsigned, x);
    u += 0x7fffu + ((u >> 16) & 1u);          // RNE
    return (short)(u >> 16);
}

// async global->LDS, 16B per lane. lds dst must be wave-uniform base; HW scatters lane*16.
__device__ __forceinline__ void load_lds16(const void* g, void* l) {
    __builtin_amdgcn_global_load_lds((const __attribute__((address_space(1))) unsigned int*)g,
                                     (__attribute__((address_space(3))) unsigned int*)l, 16, 0, 0);
}

// ---------- K0: fused converts ----------
__global__ void convert_qkv(const float* __restrict__ q, const float* __restrict__ k,
                            const float* __restrict__ v, short* __restrict__ qo,
                            short* __restrict__ ko, short* __restrict__ vo) {
    int i = blockIdx.x * 256 + threadIdx.x;   // 1048576 float4 per tensor, grid (4096,3)
    const float* s = blockIdx.y == 0 ? q : blockIdx.y == 1 ? k : v;
    short* d = blockIdx.y == 0 ? qo : blockIdx.y == 1 ? ko : vo;
    float4 val = reinterpret_cast<const float4*>(s)[i];
    short4 o; o.x = f2bf(val.x); o.y = f2bf(val.y); o.z = f2bf(val.z); o.w = f2bf(val.w);
    reinterpret_cast<short4*>(d)[i] = o;
}

__global__ void convert_w4(const float* __restrict__ w0, const float* __restrict__ w1,
                           const float* __restrict__ w2, const float* __restrict__ w3,
                           short* __restrict__ o0, short* __restrict__ o1,
                           short* __restrict__ o2, short* __restrict__ o3) {
    int i = blockIdx.x * 256 + threadIdx.x;   // 262144 float4 per tensor, grid (1024,4)
    const float* s = blockIdx.y == 0 ? w0 : blockIdx.y == 1 ? w1 : blockIdx.y == 2 ? w2 : w3;
    short* d = blockIdx.y == 0 ? o0 : blockIdx.y == 1 ? o1 : blockIdx.y == 2 ? o2 : o3;
    float4 val = reinterpret_cast<const float4*>(s)[i];
    short4 o; o.x = f2bf(val.x); o.y = f2bf(val.y); o.z = f2bf(val.z); o.w = f2bf(val.w);
    reinterpret_cast<short4*>(d)[i] = o;
}

__global__ void convert_f32_f16(const float* __restrict__ src, _Float16* __restrict__ dst, int n) {
    int i = blockIdx.x * blockDim.x + threadIdx.x;
    if (i < n) dst[i] = (_Float16)src[i];
}

// ---------- K1: geometry bias via MFMA projection; stores g (f16, [b][h][n][m]) ----------
__global__ void geom_kernel2(const float* __restrict__ boxes, const _Float16* __restrict__ Wgh,
                             const float* __restrict__ bg, __half* __restrict__ G) {
    const int tid = threadIdx.x;
    const int wave = tid >> 6, lane = tid & 63, quad = lane >> 4, l16 = lane & 15;
    const int m0 = blockIdx.x * 64;
    const int n = blockIdx.y;
    const int b = blockIdx.z;

    __shared__ __align__(16) _Float16 feat[4][16][72];
    __shared__ __align__(16) _Float16 gbuf[16][68];

    const int p = lane >> 2, c = lane & 3;
    const int m = m0 + wave * 16 + p;

    float4 bn = reinterpret_cast<const float4*>(boxes)[b * 512 + n];
    float4 bm = reinterpret_cast<const float4*>(boxes)[b * 512 + m];
    float cxn = (bn.x + bn.z) * 0.5f, cyn = (bn.y + bn.w) * 0.5f;
    float wn = bn.z - bn.x + 1.0f, hn = bn.w - bn.y + 1.0f;
    float cxm = (bm.x + bm.z) * 0.5f, cym = (bm.y + bm.w) * 0.5f;
    float wm = bm.z - bm.x + 1.0f, hm = bm.w - bm.y + 1.0f;

    float r;
    if (c == 0)      r = fmaxf(fabsf((cxn - cxm) / wn), 1e-3f);
    else if (c == 1) r = fmaxf(fabsf((cyn - cym) / hn), 1e-3f);
    else if (c == 2) r = wn / wm;
    else             r = hn / hm;
    float pos = __logf(r) * 100.0f;

    const float dm[8] = {1.0f, 0.42169651f, 0.17782794f, 0.07498942f,
                         0.03162278f, 0.01333521f, 0.00562341f, 0.00237137f};
    f16x8 sv8, cv8;
    #pragma unroll
    for (int f = 0; f < 8; ++f) {
        float th = pos * dm[f];
        sv8[f] = (_Float16)__sinf(th);
        cv8[f] = (_Float16)__cosf(th);
    }
    *(f16x8*)&feat[wave][p][c * 8]      = sv8;
    *(f16x8*)&feat[wave][p][32 + c * 8] = cv8;

    __syncthreads();

    f16x8 a0 = *(const f16x8*)&feat[wave][l16][quad * 8];
    f16x8 a1 = *(const f16x8*)&feat[wave][l16][32 + quad * 8];
    f16x8 b0 = *(const f16x8*)(Wgh + l16 * 64 + quad * 8);
    f16x8 b1 = *(const f16x8*)(Wgh + l16 * 64 + 32 + quad * 8);
    f32x4 acc = (f32x4){0.f, 0.f, 0.f, 0.f};
    acc = __builtin_amdgcn_mfma_f32_16x16x32_f16(a0, b0, acc, 0, 0, 0);
    acc = __builtin_amdgcn_mfma_f32_16x16x32_f16(a1, b1, acc, 0, 0, 0);

    float bgv = bg[l16];
    #pragma unroll
    for (int rr = 0; rr < 4; ++rr) {
        float g = fmaxf(acc[rr] + bgv, 1e-6f);        // relu + clip; store g itself
        gbuf[l16][wave * 16 + quad * 4 + rr] = (_Float16)g;
    }
    __syncthreads();

    const int h = tid >> 4, seg = tid & 15;
    ushort4 v = *(const ushort4*)&gbuf[h][seg * 4];
    *(ushort4*)&G[((long)((b * 16 + h) * 512 + n)) * 512 + m0 + seg * 4] = v;
}

// ---------- K2: ALL projections in one dispatch (Q, K, V), flat 768-block grid ----------
__global__ __launch_bounds__(256, 2)
void proj_all(const short* __restrict__ qkbf, const short* __restrict__ wqkb,
              const short* __restrict__ wvb, const short* __restrict__ vbf,
              const float* __restrict__ bq, const float* __restrict__ bk,
              const float* __restrict__ bv,
              short* __restrict__ QKh, _Float16* __restrict__ Vt) {
    __shared__ __align__(16) short As[4096];   // [128][32]
    __shared__ __align__(16) short Bs[4096];
    const int tid = threadIdx.x;
    const int wave = tid >> 6, lane = tid & 63, quad = lane >> 4, l16 = lane & 15;
    const int bid = blockIdx.x;

    const short *Ap, *Bp;
    int m0, n0, z = 0;
    bool isV = bid >= 512;
    if (!isV) {
        z = bid >> 8;
        int t = bid & 255;
        n0 = (t & 7) * 128; m0 = (t >> 3) * 128;
        Ap = qkbf + (long)z * 4194304 + (long)m0 * 1024;
        Bp = wqkb + (long)z * 1048576 + (long)n0 * 1024;
    } else {
        int t = bid - 512;
        n0 = (t & 31) * 128; m0 = (t >> 5) * 128;
        Ap = wvb + (long)m0 * 1024;
        Bp = vbf + (long)n0 * 1024;
    }

    f32x4 acc[4][4];
    #pragma unroll
    for (int mg = 0; mg < 4; ++mg)
        #pragma unroll
        for (int ng = 0; ng < 4; ++ng) acc[mg][ng] = (f32x4){0.f, 0.f, 0.f, 0.f};

    const int r0 = tid >> 2, kk = (tid & 3) * 8;
    const short* ga0 = Ap + (long)r0 * 1024 + kk;
    const short* ga1 = Ap + (long)(64 + r0) * 1024 + kk;
    const short* gb0 = Bp + (long)r0 * 1024 + kk;
    const short* gb1 = Bp + (long)(64 + r0) * 1024 + kk;
    short* la0 = As + wave * 512;
    short* la1 = As + 2048 + wave * 512;
    short* lb0 = Bs + wave * 512;
    short* lb1 = Bs + 2048 + wave * 512;

    const int mw = (wave >> 1) * 64, nw = (wave & 1) * 64;

    for (int k0 = 0; k0 < 1024; k0 += 32) {
        load_lds16(ga0 + k0, la0);
        load_lds16(ga1 + k0, la1);
        load_lds16(gb0 + k0, lb0);
        load_lds16(gb1 + k0, lb1);
        __syncthreads();
        bf16x8 a[4], bb[4];
        #pragma unroll
        for (int g = 0; g < 4; ++g) {
            a[g]  = *(const bf16x8*)&As[(mw + g * 16 + l16) * 32 + quad * 8];
            bb[g] = *(const bf16x8*)&Bs[(nw + g * 16 + l16) * 32 + quad * 8];
        }
        #pragma unroll
        for (int mg = 0; mg < 4; ++mg)
            #pragma unroll
            for (int ng = 0; ng < 4; ++ng)
                acc[mg][ng] = __builtin_amdgcn_mfma_f32_16x16x32_bf16(a[mg], bb[ng], acc[mg][ng], 0, 0, 0);
        __syncthreads();
    }

    #pragma unroll
    for (int mg = 0; mg < 4; ++mg)
        #pragma unroll
        for (int ng = 0; ng < 4; ++ng)
            #pragma unroll
            for (int r = 0; r < 4; ++r) {
                int row = m0 + mw + mg * 16 + quad * 4 + r;
                int col = n0 + nw + ng * 16 + l16;
                if (!isV) {
                    float v = acc[mg][ng][r] + (z ? bk[col] : bq[col]);
                    QKh[(long)z * 4194304 + (long)row * 1024 + col] = f2bf(v);
                } else {
                    float v = acc[mg][ng][r] + bv[row];
                    int bcol = col >> 9, lc = col & 511;    // token -> (batch, local)
                    Vt[(long)bcol * 524288 + (long)row * 512 + lc] = (_Float16)v;
                }
            }
}

// ---------- K3: flash attention, m97-style cooperative LDS staging ----------
// 256 thr = 4 waves; block = (qt 64 q-rows, h, b); wave = 16 q-rows x all 512 kv.
// Per kt: stage K(64x64 bf16), V(64x64 f16), G(64x64 f16) into padded LDS ([64][72],
// 2-way bank aliasing only = free), 2 barriers, QK/exp/g-fold/PV all from LDS.
// Grid 1024 blocks = exactly 4 blocks/CU resident -> barrier drains covered.
__global__ __launch_bounds__(256, 4)
void flash_attn6(const short* __restrict__ Q, const short* __restrict__ Kh,
                 const _Float16* __restrict__ Vt, const __half* __restrict__ G,
                 short* __restrict__ O) {
    const int tid = threadIdx.x;
    const int wave = tid >> 6, lane = tid & 63, quad = lane >> 4, l16 = lane & 15;
    const int qt = blockIdx.x, h = blockIdx.y, b = blockIdx.z;

    __shared__ __align__(16) short    Ks[64][72];        // [kv][d]
    __shared__ __align__(16) _Float16 Vs[64][72];        // [d][kv]
    __shared__ __align__(16) _Float16 Gs[64][72];        // [q][kv]
    __shared__ __align__(16) _Float16 Pbuf[4][16][72];   // per-wave private

    const int qrow = qt * 64 + wave * 16;
    const long qoff = ((long)(b * 512 + qrow + l16)) * 1024 + h * 64 + quad * 8;
    bf16x8 aq0 = *(const bf16x8*)(Q + qoff);
    bf16x8 aq1 = *(const bf16x8*)(Q + qoff + 32);

    // staging chunks: 64 rows x 8 chunks(16B) per tile; thread t -> chunks t, t+256
    const int sr0 = tid >> 3,        sc0 = (tid & 7) * 8;         // chunk t
    const int sr1 = (tid + 256) >> 3, sc1 = ((tid + 256) & 7) * 8; // chunk t+256
    const short* Kbase = Kh + (long)(b * 512) * 1024 + h * 64;
    const _Float16* Vbase = Vt + (long)b * 524288 + (long)(h * 64) * 512;
    const _Float16* Gbase = (const _Float16*)G + ((long)((b * 16 + h) * 512 + qt * 64)) * 512;

    f32x4 oacc[4];
    #pragma unroll
    for (int r = 0; r < 4; ++r) oacc[r] = (f32x4){0.f, 0.f, 0.f, 0.f};
    float rs = 0.f;   // row-sum for q = l16

    for (int kt = 0; kt < 8; ++kt) {
        __syncthreads();   // WAR: prev iter's LDS reads complete
        // cooperative staging: 6 x 16B per thread (K, V, G), coalesced 128B rows
        short8 k0 = *(const short8*)(Kbase + (long)(kt * 64 + sr0) * 1024 + sc0);
        short8 k1 = *(const short8*)(Kbase + (long)(kt * 64 + sr1) * 1024 + sc1);
        short8 v0 = *(const short8*)(Vbase + (long)sr0 * 512 + kt * 64 + sc0);
        short8 v1 = *(const short8*)(Vbase + (long)sr1 * 512 + kt * 64 + sc1);
        short8 g0 = *(const short8*)(Gbase + (long)sr0 * 512 + kt * 64 + sc0);
        short8 g1 = *(const short8*)(Gbase + (long)sr1 * 512 + kt * 64 + sc1);
        *(short8*)&Ks[sr0][sc0] = k0;
        *(short8*)&Ks[sr1][sc1] = k1;
        *(short8*)&Vs[sr0][sc0] = v0;
        *(short8*)&Vs[sr1][sc1] = v1;
        *(short8*)&Gs[sr0][sc0] = g0;
        *(short8*)&Gs[sr1][sc1] = g1;
        __syncthreads();   // tiles visible

        // QK^T from LDS
        f32x4 sc[4];
        #pragma unroll
        for (int nk = 0; nk < 4; ++nk) {
            bf16x8 bk0 = *(const bf16x8*)&Ks[nk * 16 + l16][quad * 8];
            bf16x8 bk1 = *(const bf16x8*)&Ks[nk * 16 + l16][32 + quad * 8];
            f32x4 s = (f32x4){0.f, 0.f, 0.f, 0.f};
            s = __builtin_amdgcn_mfma_f32_16x16x32_bf16(aq0, bk0, s, 0, 0, 0);
            s = __builtin_amdgcn_mfma_f32_16x16x32_bf16(aq1, bk1, s, 0, 0, 0);
            sc[nk] = s;
        }
        // exp in C-layout -> wave-private Pbuf (no barrier)
        #pragma unroll
        for (int nk = 0; nk < 4; ++nk)
            #pragma unroll
            for (int r = 0; r < 4; ++r)
                Pbuf[wave][quad * 4 + r][nk * 16 + l16] = (_Float16)__expf(sc[nk][r] * 0.125f);
        // A-frag read (q = l16, kv contiguous), fold g from LDS
        f16x8 ep0 = *(const f16x8*)&Pbuf[wave][l16][quad * 8];
        f16x8 ep1 = *(const f16x8*)&Pbuf[wave][l16][32 + quad * 8];
        f16x8 gA = *(const f16x8*)&Gs[wave * 16 + l16][quad * 8];
        f16x8 gB = *(const f16x8*)&Gs[wave * 16 + l16][32 + quad * 8];
        f16x8 gp0 = ep0 * gA;
        f16x8 gp1 = ep1 * gB;
        float part = 0.f;
        #pragma unroll
        for (int j = 0; j < 8; ++j) part += (float)gp0[j] + (float)gp1[j];
        rs += part;
        // PV (f16 MFMA) from LDS
        #pragma unroll
        for (int n4 = 0; n4 < 4; ++n4) {
            f16x8 bv0 = *(const f16x8*)&Vs[n4 * 16 + l16][quad * 8];
            f16x8 bv1 = *(const f16x8*)&Vs[n4 * 16 + l16][32 + quad * 8];
            oacc[n4] = __builtin_amdgcn_mfma_f32_16x16x32_f16(gp0, bv0, oacc[n4], 0, 0, 0);
            oacc[n4] = __builtin_amdgcn_mfma_f32_16x16x32_f16(gp1, bv1, oacc[n4], 0, 0, 0);
        }
    }

    // reduce rs over the 4 quad-partners holding the same q = l16
    rs += __shfl_xor(rs, 16);
    rs += __shfl_xor(rs, 32);
    float li[4];
    #pragma unroll
    for (int r = 0; r < 4; ++r) li[r] = __shfl(rs, quad * 4 + r);

    #pragma unroll
    for (int n4 = 0; n4 < 4; ++n4)
        #pragma unroll
        for (int r = 0; r < 4; ++r) {
            float o = oacc[n4][r] / li[r];
            O[((long)(b * 512 + qrow + quad * 4 + r)) * 1024 + h * 64 + n4 * 16 + l16] = f2bf(o);
        }
}

// ---------- K4: Wo GEMM, full-K, f32 out + bias ----------
__global__ __launch_bounds__(256, 2)
void gemm_out(const short* __restrict__ Hd, const short* __restrict__ wob,
              const float* __restrict__ bo, float* __restrict__ out) {
    __shared__ __align__(16) short As[4096];
    __shared__ __align__(16) short Bs[4096];
    const int tid = threadIdx.x;
    const int wave = tid >> 6, lane = tid & 63, quad = lane >> 4, l16 = lane & 15;
    const int m0 = blockIdx.y * 128, n0 = blockIdx.x * 128;
    const short* Ap = Hd + (long)m0 * 1024;
    const short* Bp = wob + (long)n0 * 1024;

    f32x4 acc[4][4];
    #pragma unroll
    for (int mg = 0; mg < 4; ++mg)
        #pragma unroll
        for (int ng = 0; ng < 4; ++ng) acc[mg][ng] = (f32x4){0.f, 0.f, 0.f, 0.f};

    const int r0 = tid >> 2, kk = (tid & 3) * 8;
    const short* ga0 = Ap + (long)r0 * 1024 + kk;
    const short* ga1 = Ap + (long)(64 + r0) * 1024 + kk;
    const short* gb0 = Bp + (long)r0 * 1024 + kk;
    const short* gb1 = Bp + (long)(64 + r0) * 1024 + kk;
    short* la0 = As + wave * 512;
    short* la1 = As + 2048 + wave * 512;
    short* lb0 = Bs + wave * 512;
    short* lb1 = Bs + 2048 + wave * 512;

    const int mw = (wave >> 1) * 64, nw = (wave & 1) * 64;

    for (int k0 = 0; k0 < 1024; k0 += 32) {
        load_lds16(ga0 + k0, la0);
        load_lds16(ga1 + k0, la1);
        load_lds16(gb0 + k0, lb0);
        load_lds16(gb1 + k0, lb1);
        __syncthreads();
        bf16x8 a[4], bb[4];
        #pragma unroll
        for (int g = 0; g < 4; ++g) {
            a[g]  = *(const bf16x8*)&As[(mw + g * 16 + l16) * 32 + quad * 8];
            bb[g] = *(const bf16x8*)&Bs[(nw + g * 16 + l16) * 32 + quad * 8];
        }
        #pragma unroll
        for (int mg = 0; mg < 4; ++mg)
            #pragma unroll
            for (int ng = 0; ng < 4; ++ng)
                acc[mg][ng] = __builtin_amdgcn_mfma_f32_16x16x32_bf16(a[mg], bb[ng], acc[mg][ng], 0, 0, 0);
        __syncthreads();
    }

    #pragma unroll
    for (int mg = 0; mg < 4; ++mg)
        #pragma unroll
        for (int ng = 0; ng < 4; ++ng)
            #pragma unroll
            for (int r = 0; r < 4; ++r) {
                int row = m0 + mw + mg * 16 + quad * 4 + r;
                int col = n0 + nw + ng * 16 + l16;
                out[(long)row * 1024 + col] = acc[mg][ng][r] + bo[col];
            }
}

// ---------- launch ----------
extern "C" void kernel_launch(void* const* d_in, const int* in_sizes, int n_in,
                              void* d_out, int out_size, void* d_ws, size_t ws_size,
                              hipStream_t stream) {
    const float* queries = (const float*)d_in[0];
    const float* keys    = (const float*)d_in[1];
    const float* values  = (const float*)d_in[2];
    const float* boxes   = (const float*)d_in[3];
    const float* bq = (const float*)d_in[5];
    const float* bk = (const float*)d_in[7];
    const float* bv = (const float*)d_in[9];
    const float* bo = (const float*)d_in[11];
    const float* Wg = (const float*)d_in[12];
    const float* bg = (const float*)d_in[13];

    char* ws = (char*)d_ws;
    short* qbf = (short*)(ws + 0);
    short* kbf = (short*)(ws + 8388608);
    short* vbf = (short*)(ws + 16777216);
    short* wqb = (short*)(ws + 25165824);    // wqb/wkb adjacent (z-stride 1048576 elems)
    short* wkb = (short*)(ws + 27262976);
    short* wvb = (short*)(ws + 29360128);
    short* wob = (short*)(ws + 31457280);
    short* Qh  = (short*)(ws + 33554432);    // Qh/Kh adjacent (z-stride 4194304 elems)
    _Float16* Vt = (_Float16*)(ws + 50331648);  // [b][1024 out][512 tok] f16
    short* Hd  = (short*)(ws + 58720256);    // hidden [4096][1024]
    __half* G  = (__half*)(ws + 67108864);   // g [b][h][512][512] f16, 67 MB
    _Float16* Wgh = (_Float16*)(ws + 33554432);  // overlaps Qh (dead before proj)

    convert_qkv<<<dim3(4096, 3), 256, 0, stream>>>(queries, keys, values, qbf, kbf, vbf);
    convert_w4<<<dim3(1024, 4), 256, 0, stream>>>((const float*)d_in[4], (const float*)d_in[6],
                                                  (const float*)d_in[8], (const float*)d_in[10],
                                                  wqb, wkb, wvb, wob);
    convert_f32_f16<<<4, 256, 0, stream>>>(Wg, Wgh, 1024);

    geom_kernel2<<<dim3(8, 512, 8), 256, 0, stream>>>(boxes, Wgh, bg, G);

    // all projections: 768 blocks (Q:256, K:256, V:256)
    proj_all<<<768, 256, 0, stream>>>(qbf, wqb, wvb, vbf, bq, bk, bv, Qh, Vt);

    flash_attn6<<<dim3(8, 16, 8), 256, 0, stream>>>(Qh, Qh + 4194304, Vt, G, Hd);

    // output projection -> f32 + bias
    gemm_out<<<dim3(8, 32), 256, 0, stream>>>(Hd, wob, bo, (float*)d_out);
}

// Round 10
// 277.971 us; speedup vs baseline: 1.2106x; 1.0091x over previous
//
#include <hip/hip_runtime.h>
#include <hip/hip_bf16.h>
#include <hip/hip_fp16.h>

// ---------- common types ----------
typedef __attribute__((ext_vector_type(8))) short bf16x8;      // 8 bf16 = 4 VGPR (MFMA A/B frag)
typedef __attribute__((ext_vector_type(8))) _Float16 f16x8;    // 8 f16  = 4 VGPR (MFMA A/B frag)
typedef __attribute__((ext_vector_type(4))) float f32x4;       // MFMA C/D frag
typedef __attribute__((ext_vector_type(8))) short short8;      // 16B chunk

__device__ __forceinline__ short f2bf(float x) {
    unsigned u = __builtin_bit_cast(unsigned, x);
    u += 0x7fffu + ((u >> 16) & 1u);          // RNE
    return (short)(u >> 16);
}

// async global->LDS, 16B per lane. lds dst must be wave-uniform base; HW scatters lane*16.
__device__ __forceinline__ void load_lds16(const void* g, void* l) {
    __builtin_amdgcn_global_load_lds((const __attribute__((address_space(1))) unsigned int*)g,
                                     (__attribute__((address_space(3))) unsigned int*)l, 16, 0, 0);
}

// ---------- K0: fused converts ----------
__global__ void convert_qkv(const float* __restrict__ q, const float* __restrict__ k,
                            const float* __restrict__ v, short* __restrict__ qo,
                            short* __restrict__ ko, short* __restrict__ vo) {
    int i = blockIdx.x * 256 + threadIdx.x;   // 1048576 float4 per tensor, grid (4096,3)
    const float* s = blockIdx.y == 0 ? q : blockIdx.y == 1 ? k : v;
    short* d = blockIdx.y == 0 ? qo : blockIdx.y == 1 ? ko : vo;
    float4 val = reinterpret_cast<const float4*>(s)[i];
    short4 o; o.x = f2bf(val.x); o.y = f2bf(val.y); o.z = f2bf(val.z); o.w = f2bf(val.w);
    reinterpret_cast<short4*>(d)[i] = o;
}

__global__ void convert_w4(const float* __restrict__ w0, const float* __restrict__ w1,
                           const float* __restrict__ w2, const float* __restrict__ w3,
                           short* __restrict__ o0, short* __restrict__ o1,
                           short* __restrict__ o2, short* __restrict__ o3) {
    int i = blockIdx.x * 256 + threadIdx.x;   // 262144 float4 per tensor, grid (1024,4)
    const float* s = blockIdx.y == 0 ? w0 : blockIdx.y == 1 ? w1 : blockIdx.y == 2 ? w2 : w3;
    short* d = blockIdx.y == 0 ? o0 : blockIdx.y == 1 ? o1 : blockIdx.y == 2 ? o2 : o3;
    float4 val = reinterpret_cast<const float4*>(s)[i];
    short4 o; o.x = f2bf(val.x); o.y = f2bf(val.y); o.z = f2bf(val.z); o.w = f2bf(val.w);
    reinterpret_cast<short4*>(d)[i] = o;
}

__global__ void convert_f32_f16(const float* __restrict__ src, _Float16* __restrict__ dst, int n) {
    int i = blockIdx.x * blockDim.x + threadIdx.x;
    if (i < n) dst[i] = (_Float16)src[i];
}

// ---------- K1: geometry bias via MFMA projection; stores g (f16, [b][h][n][m]) ----------
__global__ void geom_kernel2(const float* __restrict__ boxes, const _Float16* __restrict__ Wgh,
                             const float* __restrict__ bg, __half* __restrict__ G) {
    const int tid = threadIdx.x;
    const int wave = tid >> 6, lane = tid & 63, quad = lane >> 4, l16 = lane & 15;
    const int m0 = blockIdx.x * 64;
    const int n = blockIdx.y;
    const int b = blockIdx.z;

    __shared__ __align__(16) _Float16 feat[4][16][72];
    __shared__ __align__(16) _Float16 gbuf[16][68];

    const int p = lane >> 2, c = lane & 3;
    const int m = m0 + wave * 16 + p;

    float4 bn = reinterpret_cast<const float4*>(boxes)[b * 512 + n];
    float4 bm = reinterpret_cast<const float4*>(boxes)[b * 512 + m];
    float cxn = (bn.x + bn.z) * 0.5f, cyn = (bn.y + bn.w) * 0.5f;
    float wn = bn.z - bn.x + 1.0f, hn = bn.w - bn.y + 1.0f;
    float cxm = (bm.x + bm.z) * 0.5f, cym = (bm.y + bm.w) * 0.5f;
    float wm = bm.z - bm.x + 1.0f, hm = bm.w - bm.y + 1.0f;

    float r;
    if (c == 0)      r = fmaxf(fabsf((cxn - cxm) / wn), 1e-3f);
    else if (c == 1) r = fmaxf(fabsf((cyn - cym) / hn), 1e-3f);
    else if (c == 2) r = wn / wm;
    else             r = hn / hm;
    float pos = __logf(r) * 100.0f;

    const float dm[8] = {1.0f, 0.42169651f, 0.17782794f, 0.07498942f,
                         0.03162278f, 0.01333521f, 0.00562341f, 0.00237137f};
    f16x8 sv8, cv8;
    #pragma unroll
    for (int f = 0; f < 8; ++f) {
        float th = pos * dm[f];
        sv8[f] = (_Float16)__sinf(th);
        cv8[f] = (_Float16)__cosf(th);
    }
    *(f16x8*)&feat[wave][p][c * 8]      = sv8;
    *(f16x8*)&feat[wave][p][32 + c * 8] = cv8;

    __syncthreads();

    f16x8 a0 = *(const f16x8*)&feat[wave][l16][quad * 8];
    f16x8 a1 = *(const f16x8*)&feat[wave][l16][32 + quad * 8];
    f16x8 b0 = *(const f16x8*)(Wgh + l16 * 64 + quad * 8);
    f16x8 b1 = *(const f16x8*)(Wgh + l16 * 64 + 32 + quad * 8);
    f32x4 acc = (f32x4){0.f, 0.f, 0.f, 0.f};
    acc = __builtin_amdgcn_mfma_f32_16x16x32_f16(a0, b0, acc, 0, 0, 0);
    acc = __builtin_amdgcn_mfma_f32_16x16x32_f16(a1, b1, acc, 0, 0, 0);

    float bgv = bg[l16];
    #pragma unroll
    for (int rr = 0; rr < 4; ++rr) {
        float g = fmaxf(acc[rr] + bgv, 1e-6f);        // relu + clip; store g itself
        gbuf[l16][wave * 16 + quad * 4 + rr] = (_Float16)g;
    }
    __syncthreads();

    const int h = tid >> 4, seg = tid & 15;
    ushort4 v = *(const ushort4*)&gbuf[h][seg * 4];
    *(ushort4*)&G[((long)((b * 16 + h) * 512 + n)) * 512 + m0 + seg * 4] = v;
}

// ---------- K2: ALL projections, 128x64 tiles, 1536 blocks (6/CU queued) ----------
// blocks [0,1024): Q/K proj  z=bid>>9: C[tok][out] = X . W^T  (bf16, col bias)
// blocks [1024,1536): V proj         : C[out][tok] = Wv . X^T (f16 Vt, row bias)
// 4 waves stacked in M (each 32x64 = 2x4 frags). A: 2 chunks/thread, B: 1.
__global__ __launch_bounds__(256, 4)
void proj_all2(const short* __restrict__ qkbf, const short* __restrict__ wqkb,
               const short* __restrict__ wvb, const short* __restrict__ vbf,
               const float* __restrict__ bq, const float* __restrict__ bk,
               const float* __restrict__ bv,
               short* __restrict__ QKh, _Float16* __restrict__ Vt) {
    __shared__ __align__(16) short As[4096];   // [128][32]
    __shared__ __align__(16) short Bs[2048];   // [64][32]
    const int tid = threadIdx.x;
    const int wave = tid >> 6, lane = tid & 63, quad = lane >> 4, l16 = lane & 15;
    const int bid = blockIdx.x;

    const short *Ap, *Bp;
    int m0, n0, z = 0;
    bool isV = bid >= 1024;
    if (!isV) {
        z = bid >> 9;
        int t = bid & 511;
        n0 = (t & 15) * 64; m0 = (t >> 4) * 128;
        Ap = qkbf + (long)z * 4194304 + (long)m0 * 1024;
        Bp = wqkb + (long)z * 1048576 + (long)n0 * 1024;
    } else {
        int t = bid - 1024;
        n0 = (t & 63) * 64; m0 = (t >> 6) * 128;
        Ap = wvb + (long)m0 * 1024;
        Bp = vbf + (long)n0 * 1024;
    }

    f32x4 acc[2][4];
    #pragma unroll
    for (int mg = 0; mg < 2; ++mg)
        #pragma unroll
        for (int ng = 0; ng < 4; ++ng) acc[mg][ng] = (f32x4){0.f, 0.f, 0.f, 0.f};

    const int r0 = tid >> 2, kk = (tid & 3) * 8;
    const short* ga0 = Ap + (long)r0 * 1024 + kk;
    const short* ga1 = Ap + (long)(64 + r0) * 1024 + kk;
    const short* gb0 = Bp + (long)r0 * 1024 + kk;       // B has 64 rows: exactly 1 chunk/thread
    short* la0 = As + wave * 512;
    short* la1 = As + 2048 + wave * 512;
    short* lb0 = Bs + wave * 512;

    const int mw = wave * 32;

    for (int k0 = 0; k0 < 1024; k0 += 32) {
        load_lds16(ga0 + k0, la0);
        load_lds16(ga1 + k0, la1);
        load_lds16(gb0 + k0, lb0);
        __syncthreads();
        bf16x8 a[2], bb[4];
        #pragma unroll
        for (int g = 0; g < 2; ++g)
            a[g] = *(const bf16x8*)&As[(mw + g * 16 + l16) * 32 + quad * 8];
        #pragma unroll
        for (int g = 0; g < 4; ++g)
            bb[g] = *(const bf16x8*)&Bs[(g * 16 + l16) * 32 + quad * 8];
        #pragma unroll
        for (int mg = 0; mg < 2; ++mg)
            #pragma unroll
            for (int ng = 0; ng < 4; ++ng)
                acc[mg][ng] = __builtin_amdgcn_mfma_f32_16x16x32_bf16(a[mg], bb[ng], acc[mg][ng], 0, 0, 0);
        __syncthreads();
    }

    #pragma unroll
    for (int mg = 0; mg < 2; ++mg)
        #pragma unroll
        for (int ng = 0; ng < 4; ++ng)
            #pragma unroll
            for (int r = 0; r < 4; ++r) {
                int row = m0 + mw + mg * 16 + quad * 4 + r;
                int col = n0 + ng * 16 + l16;
                if (!isV) {
                    float v = acc[mg][ng][r] + (z ? bk[col] : bq[col]);
                    QKh[(long)z * 4194304 + (long)row * 1024 + col] = f2bf(v);
                } else {
                    float v = acc[mg][ng][r] + bv[row];
                    int bcol = col >> 9, lc = col & 511;    // token -> (batch, local)
                    Vt[(long)bcol * 524288 + (long)row * 512 + lc] = (_Float16)v;
                }
            }
}

// ---------- K3: flash attention, m97-style cooperative LDS staging ----------
__global__ __launch_bounds__(256, 4)
void flash_attn6(const short* __restrict__ Q, const short* __restrict__ Kh,
                 const _Float16* __restrict__ Vt, const __half* __restrict__ G,
                 short* __restrict__ O) {
    const int tid = threadIdx.x;
    const int wave = tid >> 6, lane = tid & 63, quad = lane >> 4, l16 = lane & 15;
    const int qt = blockIdx.x, h = blockIdx.y, b = blockIdx.z;

    __shared__ __align__(16) short    Ks[64][72];        // [kv][d]
    __shared__ __align__(16) _Float16 Vs[64][72];        // [d][kv]
    __shared__ __align__(16) _Float16 Gs[64][72];        // [q][kv]
    __shared__ __align__(16) _Float16 Pbuf[4][16][72];   // per-wave private

    const int qrow = qt * 64 + wave * 16;
    const long qoff = ((long)(b * 512 + qrow + l16)) * 1024 + h * 64 + quad * 8;
    bf16x8 aq0 = *(const bf16x8*)(Q + qoff);
    bf16x8 aq1 = *(const bf16x8*)(Q + qoff + 32);

    const int sr0 = tid >> 3,         sc0 = (tid & 7) * 8;
    const int sr1 = (tid + 256) >> 3, sc1 = ((tid + 256) & 7) * 8;
    const short* Kbase = Kh + (long)(b * 512) * 1024 + h * 64;
    const _Float16* Vbase = Vt + (long)b * 524288 + (long)(h * 64) * 512;
    const _Float16* Gbase = (const _Float16*)G + ((long)((b * 16 + h) * 512 + qt * 64)) * 512;

    f32x4 oacc[4];
    #pragma unroll
    for (int r = 0; r < 4; ++r) oacc[r] = (f32x4){0.f, 0.f, 0.f, 0.f};
    float rs = 0.f;

    for (int kt = 0; kt < 8; ++kt) {
        __syncthreads();
        short8 k0 = *(const short8*)(Kbase + (long)(kt * 64 + sr0) * 1024 + sc0);
        short8 k1 = *(const short8*)(Kbase + (long)(kt * 64 + sr1) * 1024 + sc1);
        short8 v0 = *(const short8*)(Vbase + (long)sr0 * 512 + kt * 64 + sc0);
        short8 v1 = *(const short8*)(Vbase + (long)sr1 * 512 + kt * 64 + sc1);
        short8 g0 = *(const short8*)(Gbase + (long)sr0 * 512 + kt * 64 + sc0);
        short8 g1 = *(const short8*)(Gbase + (long)sr1 * 512 + kt * 64 + sc1);
        *(short8*)&Ks[sr0][sc0] = k0;
        *(short8*)&Ks[sr1][sc1] = k1;
        *(short8*)&Vs[sr0][sc0] = v0;
        *(short8*)&Vs[sr1][sc1] = v1;
        *(short8*)&Gs[sr0][sc0] = g0;
        *(short8*)&Gs[sr1][sc1] = g1;
        __syncthreads();

        f32x4 sc[4];
        #pragma unroll
        for (int nk = 0; nk < 4; ++nk) {
            bf16x8 bk0 = *(const bf16x8*)&Ks[nk * 16 + l16][quad * 8];
            bf16x8 bk1 = *(const bf16x8*)&Ks[nk * 16 + l16][32 + quad * 8];
            f32x4 s = (f32x4){0.f, 0.f, 0.f, 0.f};
            s = __builtin_amdgcn_mfma_f32_16x16x32_bf16(aq0, bk0, s, 0, 0, 0);
            s = __builtin_amdgcn_mfma_f32_16x16x32_bf16(aq1, bk1, s, 0, 0, 0);
            sc[nk] = s;
        }
        #pragma unroll
        for (int nk = 0; nk < 4; ++nk)
            #pragma unroll
            for (int r = 0; r < 4; ++r)
                Pbuf[wave][quad * 4 + r][nk * 16 + l16] = (_Float16)__expf(sc[nk][r] * 0.125f);
        f16x8 ep0 = *(const f16x8*)&Pbuf[wave][l16][quad * 8];
        f16x8 ep1 = *(const f16x8*)&Pbuf[wave][l16][32 + quad * 8];
        f16x8 gA = *(const f16x8*)&Gs[wave * 16 + l16][quad * 8];
        f16x8 gB = *(const f16x8*)&Gs[wave * 16 + l16][32 + quad * 8];
        f16x8 gp0 = ep0 * gA;
        f16x8 gp1 = ep1 * gB;
        float part = 0.f;
        #pragma unroll
        for (int j = 0; j < 8; ++j) part += (float)gp0[j] + (float)gp1[j];
        rs += part;
        #pragma unroll
        for (int n4 = 0; n4 < 4; ++n4) {
            f16x8 bv0 = *(const f16x8*)&Vs[n4 * 16 + l16][quad * 8];
            f16x8 bv1 = *(const f16x8*)&Vs[n4 * 16 + l16][32 + quad * 8];
            oacc[n4] = __builtin_amdgcn_mfma_f32_16x16x32_f16(gp0, bv0, oacc[n4], 0, 0, 0);
            oacc[n4] = __builtin_amdgcn_mfma_f32_16x16x32_f16(gp1, bv1, oacc[n4], 0, 0, 0);
        }
    }

    rs += __shfl_xor(rs, 16);
    rs += __shfl_xor(rs, 32);
    float li[4];
    #pragma unroll
    for (int r = 0; r < 4; ++r) li[r] = __shfl(rs, quad * 4 + r);

    #pragma unroll
    for (int n4 = 0; n4 < 4; ++n4)
        #pragma unroll
        for (int r = 0; r < 4; ++r) {
            float o = oacc[n4][r] / li[r];
            O[((long)(b * 512 + qrow + quad * 4 + r)) * 1024 + h * 64 + n4 * 16 + l16] = f2bf(o);
        }
}

// ---------- K4: Wo GEMM, 128x64 tiles, 512 blocks ----------
__global__ __launch_bounds__(256, 4)
void gemm_out2(const short* __restrict__ Hd, const short* __restrict__ wob,
               const float* __restrict__ bo, float* __restrict__ out) {
    __shared__ __align__(16) short As[4096];   // [128][32]
    __shared__ __align__(16) short Bs[2048];   // [64][32]
    const int tid = threadIdx.x;
    const int wave = tid >> 6, lane = tid & 63, quad = lane >> 4, l16 = lane & 15;
    const int m0 = blockIdx.y * 128, n0 = blockIdx.x * 64;
    const short* Ap = Hd + (long)m0 * 1024;
    const short* Bp = wob + (long)n0 * 1024;

    f32x4 acc[2][4];
    #pragma unroll
    for (int mg = 0; mg < 2; ++mg)
        #pragma unroll
        for (int ng = 0; ng < 4; ++ng) acc[mg][ng] = (f32x4){0.f, 0.f, 0.f, 0.f};

    const int r0 = tid >> 2, kk = (tid & 3) * 8;
    const short* ga0 = Ap + (long)r0 * 1024 + kk;
    const short* ga1 = Ap + (long)(64 + r0) * 1024 + kk;
    const short* gb0 = Bp + (long)r0 * 1024 + kk;
    short* la0 = As + wave * 512;
    short* la1 = As + 2048 + wave * 512;
    short* lb0 = Bs + wave * 512;

    const int mw = wave * 32;

    for (int k0 = 0; k0 < 1024; k0 += 32) {
        load_lds16(ga0 + k0, la0);
        load_lds16(ga1 + k0, la1);
        load_lds16(gb0 + k0, lb0);
        __syncthreads();
        bf16x8 a[2], bb[4];
        #pragma unroll
        for (int g = 0; g < 2; ++g)
            a[g] = *(const bf16x8*)&As[(mw + g * 16 + l16) * 32 + quad * 8];
        #pragma unroll
        for (int g = 0; g < 4; ++g)
            bb[g] = *(const bf16x8*)&Bs[(g * 16 + l16) * 32 + quad * 8];
        #pragma unroll
        for (int mg = 0; mg < 2; ++mg)
            #pragma unroll
            for (int ng = 0; ng < 4; ++ng)
                acc[mg][ng] = __builtin_amdgcn_mfma_f32_16x16x32_bf16(a[mg], bb[ng], acc[mg][ng], 0, 0, 0);
        __syncthreads();
    }

    #pragma unroll
    for (int mg = 0; mg < 2; ++mg)
        #pragma unroll
        for (int ng = 0; ng < 4; ++ng)
            #pragma unroll
            for (int r = 0; r < 4; ++r) {
                int row = m0 + mw + mg * 16 + quad * 4 + r;
                int col = n0 + ng * 16 + l16;
                out[(long)row * 1024 + col] = acc[mg][ng][r] + bo[col];
            }
}

// ---------- launch ----------
extern "C" void kernel_launch(void* const* d_in, const int* in_sizes, int n_in,
                              void* d_out, int out_size, void* d_ws, size_t ws_size,
                              hipStream_t stream) {
    const float* queries = (const float*)d_in[0];
    const float* keys    = (const float*)d_in[1];
    const float* values  = (const float*)d_in[2];
    const float* boxes   = (const float*)d_in[3];
    const float* bq = (const float*)d_in[5];
    const float* bk = (const float*)d_in[7];
    const float* bv = (const float*)d_in[9];
    const float* bo = (const float*)d_in[11];
    const float* Wg = (const float*)d_in[12];
    const float* bg = (const float*)d_in[13];

    char* ws = (char*)d_ws;
    short* qbf = (short*)(ws + 0);
    short* kbf = (short*)(ws + 8388608);
    short* vbf = (short*)(ws + 16777216);
    short* wqb = (short*)(ws + 25165824);    // wqb/wkb adjacent (z-stride 1048576 elems)
    short* wkb = (short*)(ws + 27262976);
    short* wvb = (short*)(ws + 29360128);
    short* wob = (short*)(ws + 31457280);
    short* Qh  = (short*)(ws + 33554432);    // Qh/Kh adjacent (z-stride 4194304 elems)
    _Float16* Vt = (_Float16*)(ws + 50331648);  // [b][1024 out][512 tok] f16
    short* Hd  = (short*)(ws + 58720256);    // hidden [4096][1024]
    __half* G  = (__half*)(ws + 67108864);   // g [b][h][512][512] f16, 67 MB
    _Float16* Wgh = (_Float16*)(ws + 33554432);  // overlaps Qh (dead before proj)

    convert_qkv<<<dim3(4096, 3), 256, 0, stream>>>(queries, keys, values, qbf, kbf, vbf);
    convert_w4<<<dim3(1024, 4), 256, 0, stream>>>((const float*)d_in[4], (const float*)d_in[6],
                                                  (const float*)d_in[8], (const float*)d_in[10],
                                                  wqb, wkb, wvb, wob);
    convert_f32_f16<<<4, 256, 0, stream>>>(Wg, Wgh, 1024);

    geom_kernel2<<<dim3(8, 512, 8), 256, 0, stream>>>(boxes, Wgh, bg, G);

    // all projections: 1536 blocks (Q:512, K:512, V:512) = 6 blocks/CU queued
    proj_all2<<<1536, 256, 0, stream>>>(qbf, wqb, wvb, vbf, bq, bk, bv, Qh, Vt);

    flash_attn6<<<dim3(8, 16, 8), 256, 0, stream>>>(Qh, Qh + 4194304, Vt, G, Hd);

    // output projection -> f32 + bias, 512 blocks
    gemm_out2<<<dim3(16, 32), 256, 0, stream>>>(Hd, wob, bo, (float*)d_out);
}